// Round 2
// baseline (964.522 us; speedup 1.0000x reference)
//
#include <hip/hip_runtime.h>

// Problem constants (from reference)
#define F_XC 64
#define F_UC 128
#define F_OUTC 128
#define B_GLOB 512

// ---------------------------------------------------------------------------
// Phase 1: edge scatter.  agg[dest][f] += attr[e] * x[src][f]
// One 64-lane group per edge; lane f handles feature f.
// src/dest/attr loads are wave-uniform (broadcast); x row load is one
// coalesced 256B transaction; atomic row hits 4 cachelines of agg.
// ---------------------------------------------------------------------------
__global__ __launch_bounds__(256) void scatter_kernel(
    const int* __restrict__ src, const int* __restrict__ dst,
    const float* __restrict__ attr, const float* __restrict__ x,
    float* __restrict__ agg, int E)
{
    int e = blockIdx.x * 4 + (threadIdx.x >> 6);
    int f = threadIdx.x & 63;
    if (e >= E) return;
    int s = src[e];
    int d = dst[e];
    float a = attr[e];
    float xv = x[(size_t)s * F_XC + f];
    atomicAdd(&agg[(size_t)d * F_XC + f], a * xv);
}

// ---------------------------------------------------------------------------
// Phase 2: per-batch global projection.
// UK[b][j] = b_K[j] + sum_k u[b][k] * W_K[64+k][j]   (and same for Q)
// B=512 blocks x 128 threads; trivial FLOPs.
// ---------------------------------------------------------------------------
__global__ __launch_bounds__(128) void global_proj_kernel(
    const float* __restrict__ u, const float* __restrict__ W_K,
    const float* __restrict__ b_K, const float* __restrict__ W_Q,
    const float* __restrict__ b_Q, float* __restrict__ UK,
    float* __restrict__ UQ)
{
    __shared__ float s_u[F_UC];
    int b = blockIdx.x;
    int j = threadIdx.x;
    s_u[j] = u[(size_t)b * F_UC + j];
    __syncthreads();
    float accK = b_K[j];
    float accQ = b_Q[j];
    #pragma unroll 8
    for (int k = 0; k < F_UC; ++k) {
        float uv = s_u[k];
        accK = fmaf(uv, W_K[(size_t)(F_XC + k) * F_OUTC + j], accK);
        accQ = fmaf(uv, W_Q[(size_t)(F_XC + k) * F_OUTC + j], accQ);
    }
    UK[(size_t)b * F_OUTC + j] = accK;
    UQ[(size_t)b * F_OUTC + j] = accQ;
}

// ---------------------------------------------------------------------------
// Phase 3: output GEMM.
// K[n][j] = sum_{k<64} agg[n][k] * W_K[k][j] + UK[batch[n]][j]
// Block = 256 threads = 2 nodes x 128 output features.
// Weight columns live in registers (64+64 VGPRs); agg row broadcast via LDS.
// Grid-stride so the weight load (64KB cached) amortizes over ~25 nodes/blk.
// ---------------------------------------------------------------------------
__global__ __launch_bounds__(256) void out_kernel(
    const float* __restrict__ agg, const int* __restrict__ batch,
    const float* __restrict__ W_K, const float* __restrict__ W_Q,
    const float* __restrict__ UK, const float* __restrict__ UQ,
    float* __restrict__ K_out, float* __restrict__ Q_out, int nodes)
{
    const int j = threadIdx.x & 127;
    const int half = threadIdx.x >> 7;

    float wk[F_XC], wq[F_XC];
    #pragma unroll
    for (int k = 0; k < F_XC; ++k) {
        wk[k] = W_K[(size_t)k * F_OUTC + j];
        wq[k] = W_Q[(size_t)k * F_OUTC + j];
    }

    __shared__ float s_agg[2][F_XC];

    for (int base = blockIdx.x * 2; base < nodes; base += gridDim.x * 2) {
        const int n = base + half;
        __syncthreads();   // protect s_agg reads from previous iteration
        if (threadIdx.x < 64) {
            s_agg[0][threadIdx.x] = agg[(size_t)base * F_XC + threadIdx.x];
        } else if (threadIdx.x >= 128 && threadIdx.x < 192) {
            int n1 = base + 1;
            s_agg[1][threadIdx.x - 128] =
                (n1 < nodes) ? agg[(size_t)n1 * F_XC + (threadIdx.x - 128)] : 0.f;
        }
        __syncthreads();
        if (n < nodes) {
            float accK = 0.f, accQ = 0.f;
            #pragma unroll
            for (int k = 0; k < F_XC; ++k) {
                float av = s_agg[half][k];
                accK = fmaf(av, wk[k], accK);
                accQ = fmaf(av, wq[k], accQ);
            }
            const int bb = batch[n];
            K_out[(size_t)n * F_OUTC + j] = accK + UK[(size_t)bb * F_OUTC + j];
            Q_out[(size_t)n * F_OUTC + j] = accQ + UQ[(size_t)bb * F_OUTC + j];
        }
    }
}

// ---------------------------------------------------------------------------
// Launch
// ---------------------------------------------------------------------------
extern "C" void kernel_launch(void* const* d_in, const int* in_sizes, int n_in,
                              void* d_out, int out_size, void* d_ws, size_t ws_size,
                              hipStream_t stream) {
    const float* x         = (const float*)d_in[0];
    const int*   edge_idx  = (const int*)  d_in[1];
    const float* edge_attr = (const float*)d_in[2];
    const float* u         = (const float*)d_in[3];
    const int*   batch     = (const int*)  d_in[4];
    const float* W_K       = (const float*)d_in[5];
    const float* b_K       = (const float*)d_in[6];
    const float* W_Q       = (const float*)d_in[7];
    const float* b_Q       = (const float*)d_in[8];

    const int N = in_sizes[0] / F_XC;       // 100000
    const int E = in_sizes[1] / 2;          // 3200000

    // workspace layout: agg [N*64] | UK [B*128] | UQ [B*128]
    float* agg = (float*)d_ws;
    float* UK  = agg + (size_t)N * F_XC;
    float* UQ  = UK + (size_t)B_GLOB * F_OUTC;

    float* K_out = (float*)d_out;
    float* Q_out = K_out + (size_t)N * F_OUTC;

    hipMemsetAsync(agg, 0, (size_t)N * F_XC * sizeof(float), stream);

    const int* src = edge_idx;
    const int* dst = edge_idx + E;

    scatter_kernel<<<(E + 3) / 4, 256, 0, stream>>>(src, dst, edge_attr, x, agg, E);
    global_proj_kernel<<<B_GLOB, 128, 0, stream>>>(u, W_K, b_K, W_Q, b_Q, UK, UQ);
    out_kernel<<<2048, 256, 0, stream>>>(agg, batch, W_K, W_Q, UK, UQ,
                                          K_out, Q_out, N);
}